// Round 1
// baseline (365.568 us; speedup 1.0000x reference)
//
#include <hip/hip_runtime.h>
#include <hip/hip_bf16.h>

// MultiScaleRetention forward. Inputs/outputs FLOAT32; internals bf16 MFMA.
//   0) convert x -> xb (bf16); transpose weights f32 -> bf16
//   1) GEMM1 (m97-style, global_load_lds staging): xb @ Wt^T; LEAN epilogue,
//      ALL-COALESCED: qk -> f32 Cqk (+bias,+k-scale); v -> bf16 vbuf; g -> f32
//   2) vtrans: vbuf (b, s, 2048) -> vT (bh, 128, S)
//   3) router: rotary (f32) + hi/lo bf16 split + (bh,S,64) layout for q,k
//   4) retention: PAIRED m-stripes; R11: 32-row half-stripe pairs, 2-wave
//      blocks, grid 1024 -> 4 independent blocks/CU (R10's 512 blocks = 2/CU
//      was the bottleneck: no pipe >27% busy, ~25% of cycles were stalls with
//      only 2 streams/CU; R9's imbalanced 1024-block version beat R10).
//      Per-wave body identical to R10 (shared K/V LDS tile AND shared K/V
//      register fragments between the two stripes; double-buffered staging).
//      Co-resident blocks (bid +256 -> seg bit3 flip) get complementary px
//      so each CU's 4 blocks sum to uniform 194 iterations.
//   5) GEMM2: gated @ oT^T + o_b -> d_out (f32)
//
// Per-stripe math bit-identical to R9/R10 -> absmax must stay 0.01049805.

typedef __hip_bfloat16 bf16;
typedef short bf16x4 __attribute__((ext_vector_type(4)));
typedef short bf16x8 __attribute__((ext_vector_type(8)));
typedef float floatx4 __attribute__((ext_vector_type(4)));

#define B_SZ 2
#define SEQ 2048
#define NH 16
#define KD 64
#define HD 128

// global->LDS direct copy, 16B/lane. LDS dest is wave-uniform base + lane*16.
#define ASYNC16(gp, lp)                                                             \
  __builtin_amdgcn_global_load_lds(                                                 \
      (const __attribute__((address_space(1))) unsigned int*)(unsigned long long)(const void*)(gp), \
      (__attribute__((address_space(3))) unsigned int*)(unsigned int)(unsigned long long)(void*)(lp), \
      16, 0, 0)

__device__ __forceinline__ float b2f(bf16 x) { return __bfloat162float(x); }
__device__ __forceinline__ bf16 f2b(float x) { return __float2bfloat16(x); }

// ---------------- f32 -> bf16 convert (x) ----------------
__global__ void convert_k(const float* __restrict__ in, bf16* __restrict__ out) {
  int i = blockIdx.x * 256 + threadIdx.x;  // one float4 per thread
  float4 v = reinterpret_cast<const float4*>(in)[i];
  union { bf16 h[4]; bf16x4 v4; } u;
  u.h[0] = f2b(v.x); u.h[1] = f2b(v.y); u.h[2] = f2b(v.z); u.h[3] = f2b(v.w);
  reinterpret_cast<bf16x4*>(out)[i] = u.v4;
}

// ---------------- weight transpose: in f32 (K,N) -> out bf16 (N,K) --------
__global__ void transpose_k(const float* __restrict__ in, bf16* __restrict__ out,
                            int K, int N) {
  __shared__ float tile[32][33];
  int tx = threadIdx.x, ty = threadIdx.y;
  int n0 = blockIdx.x * 32, k0 = blockIdx.y * 32;
#pragma unroll
  for (int j = 0; j < 4; ++j)
    tile[ty + j * 8][tx] = in[(size_t)(k0 + ty + j * 8) * N + n0 + tx];
  __syncthreads();
#pragma unroll
  for (int j = 0; j < 4; ++j)
    out[(size_t)(n0 + ty + j * 8) * K + k0 + tx] = f2b(tile[tx][ty + j * 8]);
}

// ---------------- v transpose: per-b 2048x2048 bf16 ----------------
__global__ void vtrans_k(const bf16* __restrict__ in, bf16* __restrict__ out) {
  __shared__ bf16 tile[32][34];
  int tx = threadIdx.x, ty = threadIdx.y;
  int s0 = blockIdx.x * 32, c0 = blockIdx.y * 32;
  const bf16* src = in + (size_t)blockIdx.z * 2048 * 2048;
  bf16* dst = out + (size_t)blockIdx.z * 2048 * 2048;
#pragma unroll
  for (int j = 0; j < 4; ++j)
    tile[ty + j * 8][tx] = src[(size_t)(s0 + ty + j * 8) * 2048 + c0 + tx];
  __syncthreads();
#pragma unroll
  for (int j = 0; j < 4; ++j)
    dst[(size_t)(c0 + ty + j * 8) * 2048 + s0 + tx] = tile[tx][ty + j * 8];
}

// ---------------- GEMM: C(M,N) = A(M,K) @ Bt(N,K)^T ----------------
template <int BM, int BN, int KDIM, int MODE>
__global__ __launch_bounds__(256, 2) void gemm_bt(
    const bf16* __restrict__ A, const bf16* __restrict__ Bt, int Ndim,
    const float* __restrict__ bias_q, const float* __restrict__ bias_k,
    const float* __restrict__ bias_v, const float* __restrict__ bias_g,
    float* __restrict__ outCqk, bf16* __restrict__ out_v,
    float* __restrict__ out_g, float* __restrict__ outF) {
  __shared__ bf16 As[BM * 32];
  __shared__ bf16 Bs[BN * 32];
  const int tid = threadIdx.x;
  const int wave = tid >> 6, lane = tid & 63;
  const int quad = lane >> 4, l16 = lane & 15;
  const int m0 = blockIdx.y * BM, n0 = blockIdx.x * BN;
  constexpr int FI = BM / 32;
  constexpr int FJ = BN / 32;
  const int wm = (wave >> 1) * (BM / 2), wn = (wave & 1) * (BN / 2);

  floatx4 acc[FI][FJ] = {};

  for (int k0 = 0; k0 < KDIM; k0 += 32) {
#pragma unroll
    for (int j = 0; j < BM / 64; ++j) {
      int cbase = (j * 4 + wave) * 64;
      int c = cbase + lane;
      const bf16* g = A + (size_t)(m0 + (c >> 2)) * KDIM + k0 + (c & 3) * 8;
      ASYNC16(g, &As[cbase * 8]);
    }
#pragma unroll
    for (int j = 0; j < BN / 64; ++j) {
      int cbase = (j * 4 + wave) * 64;
      int c = cbase + lane;
      const bf16* g = Bt + (size_t)(n0 + (c >> 2)) * KDIM + k0 + (c & 3) * 8;
      ASYNC16(g, &Bs[cbase * 8]);
    }
    __syncthreads();  // compiler drains vmcnt(0) before s_barrier

    bf16x8 af[FI], bfr[FJ];
#pragma unroll
    for (int i = 0; i < FI; ++i)
      af[i] = *(const bf16x8*)&As[(wm + i * 16 + l16) * 32 + quad * 8];
#pragma unroll
    for (int j = 0; j < FJ; ++j)
      bfr[j] = *(const bf16x8*)&Bs[(wn + j * 16 + l16) * 32 + quad * 8];
#pragma unroll
    for (int i = 0; i < FI; ++i)
#pragma unroll
      for (int j = 0; j < FJ; ++j)
        acc[i][j] = __builtin_amdgcn_mfma_f32_16x16x32_bf16(af[i], bfr[j],
                                                            acc[i][j], 0, 0, 0);
    __syncthreads();
  }

  // LEAN epilogue, all stores coalesced
#pragma unroll
  for (int i = 0; i < FI; ++i) {
#pragma unroll
    for (int j = 0; j < FJ; ++j) {
#pragma unroll
      for (int r = 0; r < 4; ++r) {
        int gm = m0 + wm + i * 16 + quad * 4 + r;
        int gn = n0 + wn + j * 16 + l16;
        float v = acc[i][j][r];
        if (MODE == 1) {
          v += bias_q[gn];  // bias_q = o_b
          outF[(size_t)gm * Ndim + gn] = v;
        } else {
          if (gn < 2048) {
            bool is_k = gn >= 1024;
            int jj = is_k ? gn - 1024 : gn;
            v += is_k ? bias_k[jj] : bias_q[jj];
            if (is_k) v *= 0.125f;  // SCALING = KEY_DIM^-0.5
            outCqk[(size_t)gm * 2048 + gn] = v;  // f32, exact
          } else if (gn < 4096) {
            int jj = gn - 2048;
            v += bias_v[jj];
            out_v[(size_t)gm * 2048 + jj] = f2b(v);  // natural layout
          } else {
            int jj = gn - 4096;
            v += bias_g[jj];
            out_g[(size_t)gm * 2048 + jj] = v;  // f32
          }
        }
      }
    }
  }
}

// ---------------- router: rotary + hi/lo split + layout ----------------
__global__ void router_k(const float* __restrict__ Cqk,
                         bf16* __restrict__ qh, bf16* __restrict__ ql,
                         bf16* __restrict__ kh, bf16* __restrict__ kl) {
  int t = blockIdx.x * 256 + threadIdx.x;  // 4096*1024 threads
  int row = t >> 10, pc = t & 1023;
  int b = row >> 11, s = row & 2047;
  bool is_k = pc >= 512;
  int jj = (pc - (is_k ? 512 : 0)) * 2;  // even, 0..1022
  int h = jj >> 6, d = jj & 63, ii = d >> 1;
  float2 v = *(const float2*)&Cqk[(size_t)row * 2048 + pc * 2];
  float half = exp2f(-(float)ii * (13.287712379549449f / 31.0f));
  float ang = (float)s * half;
  float sn = sinf(ang), cs = cosf(ang);
  float e = v.x * cs - v.y * sn;
  float o = v.y * cs + v.x * sn;
  bf16 eh = f2b(e), oh = f2b(o);
  bf16 el = f2b(e - b2f(eh)), ol = f2b(o - b2f(oh));
  size_t idx = (((size_t)b * NH + h) * SEQ + s) * KD + d;
  bf16* ph = is_k ? kh : qh;
  bf16* pl = is_k ? kl : ql;
  union { bf16 h2[2]; unsigned u; } uh, ul;
  uh.h2[0] = eh; uh.h2[1] = oh;
  ul.h2[0] = el; ul.h2[1] = ol;
  *(unsigned*)&ph[idx] = uh.u;
  *(unsigned*)&pl[idx] = ul.u;
}

// ---------------- retention core (R11: 32-row half-stripe pairs) ----------
// grid 1024 flat; bid -> (seg = bid>>5 -> h=seg&15, b=seg>>4), px_raw=bid&31.
// px = (seg bit3) ? 31-px_raw : px_raw  -> co-resident blocks (bid+256) get
// complementary px so each CU's 4 blocks total a uniform 194 iterations.
// Block px owns TWO 32-row half-stripes: heavy bt_h=63-px, light bt_l=px
// -> uniform 65 tile-computes per block. 2 waves x 16 rows per stripe; one
// n-tile loop over the heavy range; light stripe computed while in its own
// (prefix) range, REUSING the K/V register fragments of the heavy stripe.
// Double-buffered LDS staging with explicit vmcnt drain. Per-stripe math
// identical to R9/R10.
__global__ __launch_bounds__(128, 2) void retention_k(
    const bf16* __restrict__ qh, const bf16* __restrict__ ql,
    const bf16* __restrict__ kh, const bf16* __restrict__ kl,
    const bf16* __restrict__ vT, const float* __restrict__ g,
    bf16* __restrict__ gated) {
  __shared__ bf16 KHs[2][32 * 64];
  __shared__ bf16 KLs[2][32 * 64];
  __shared__ bf16 Vs[2][128 * 32];
  __shared__ bf16 Plh[2][16 * 32];
  __shared__ bf16 Pll[2][16 * 32];
  const int tid = threadIdx.x;
  const int wave = tid >> 6, lane = tid & 63;
  const int quad = lane >> 4, l16 = lane & 15;
  const int bid = blockIdx.x;
  const int px_raw = bid & 31;
  const int seg = bid >> 5;           // 0..31
  const int h = seg & 15, b = seg >> 4;
  const int px = ((seg >> 3) & 1) ? (31 - px_raw) : px_raw;
  const int bh = b * NH + h;
  const int bt_h = 63 - px;           // heavy half-stripe (32 rows)
  const int bt_l = px;                // light half-stripe
  const int m0h = bt_h * 32 + wave * 16;
  const int m0l = bt_l * 32 + wave * 16;
  const int ntiles = bt_h + 1;
  const int lt_ntiles = bt_l + 1;

  const float t = exp2f(-(float)(5 + h));  // 1-gamma (exact)
  const float lng = log1pf(-t);            // ln(gamma)
  const float log2g = lng * 1.44269504088896340736f;

  float rfh[4], rfl[4];
#pragma unroll
  for (int r = 0; r < 4; ++r) {
    int mh = m0h + quad * 4 + r;
    int ml = m0l + quad * 4 + r;
    rfh[r] = exp2f((float)mh * log2g) *
             rsqrtf(-expm1f((float)(mh + 1) * lng) / t);
    rfl[r] = exp2f((float)ml * log2g) *
             rsqrtf(-expm1f((float)(ml + 1) * lng) / t);
  }
  const float gstep = exp2f(-32.0f * log2g);      // gamma^-32
  const float cf0 = exp2f(-(float)l16 * log2g);   // gamma^-l16
  const float cf1 = cf0 * exp2f(-16.0f * log2g);  // gamma^-(16+l16)

  const size_t qoffh = ((size_t)bh * SEQ + m0h + l16) * KD;
  const size_t qoffl = ((size_t)bh * SEQ + m0l + l16) * KD;
  bf16x8 aq0h_h = *(const bf16x8*)&qh[qoffh + quad * 8];
  bf16x8 aq1h_h = *(const bf16x8*)&qh[qoffh + 32 + quad * 8];
  bf16x8 aq0l_h = *(const bf16x8*)&ql[qoffh + quad * 8];
  bf16x8 aq1l_h = *(const bf16x8*)&ql[qoffh + 32 + quad * 8];
  bf16x8 aq0h_l = *(const bf16x8*)&qh[qoffl + quad * 8];
  bf16x8 aq1h_l = *(const bf16x8*)&qh[qoffl + 32 + quad * 8];
  bf16x8 aq0l_l = *(const bf16x8*)&ql[qoffl + quad * 8];
  bf16x8 aq1l_l = *(const bf16x8*)&ql[qoffl + 32 + quad * 8];

  floatx4 oacch[8] = {}, oaccl[8] = {};
  float rsh[4] = {0.f, 0.f, 0.f, 0.f}, rsl[4] = {0.f, 0.f, 0.f, 0.f};

  const bf16* khb = kh + (size_t)bh * SEQ * KD;
  const bf16* klb = kl + (size_t)bh * SEQ * KD;
  const bf16* vbase = vT + (size_t)bh * HD * SEQ;

  // 16 x 1KB chunks per tile, split over 2 waves: wave0 -> K (hi+lo),
  // wave1 -> V. Same swizzled layouts as R10.
  auto stage = [&](int nt, int buf) {
    const int n0s = nt * 32;
#pragma unroll
    for (int j = 0; j < 8; ++j) {
      int cc = wave * 8 + j;
      if (cc < 8) {
        const bf16* src = (cc < 4) ? khb : klb;
        bf16* dst = (cc < 4) ? KHs[buf] : KLs[buf];
        int r = ((cc & 3) * 8) + (lane >> 3);
        int s = lane & 7;
        int q = (s - r) & 7;
        ASYNC16(src + (size_t)(n0s + r) * KD + q * 8, &dst[(cc & 3) * 512]);
      } else {
        int r = (cc - 8) * 16 + (lane >> 2);
        int s = lane & 3;
        int q = (s - (r >> 1)) & 3;
        ASYNC16(vbase + (size_t)r * SEQ + n0s + q * 8, &Vs[buf][(cc - 8) * 512]);
      }
    }
  };

  stage(0, 0);
  for (int nt = 0; nt < ntiles; ++nt) {
    const int n0 = nt * 32;
    const int cur = nt & 1;
    asm volatile("s_waitcnt vmcnt(0) lgkmcnt(0)" ::: "memory");
    __syncthreads();
    {
      int pf = (nt + 1 < ntiles) ? nt + 1 : nt;
      stage(pf, cur ^ 1);
    }

    const bool hact = (n0 <= m0h + 15);
    const bool lact = (n0 <= m0l + 15);

    // ---- QK for both stripes, sharing K fragments ----
    floatx4 sch[2], scl[2];
#pragma unroll
    for (int hh = 0; hh < 2; ++hh) {
      int krow = hh * 16 + l16;
      int c0 = ((quad + krow) & 7) * 8;
      int c1 = ((quad + 4 + krow) & 7) * 8;
      bf16x8 bkh0 = *(const bf16x8*)&KHs[cur][krow * 64 + c0];
      bf16x8 bkh1 = *(const bf16x8*)&KHs[cur][krow * 64 + c1];
      bf16x8 bkl0 = *(const bf16x8*)&KLs[cur][krow * 64 + c0];
      bf16x8 bkl1 = *(const bf16x8*)&KLs[cur][krow * 64 + c1];
      if (hact) {
        floatx4 z1 = {0.f, 0.f, 0.f, 0.f}, z2 = z1, z3 = z1;
        z1 = __builtin_amdgcn_mfma_f32_16x16x32_bf16(aq0h_h, bkh0, z1, 0, 0, 0);
        z2 = __builtin_amdgcn_mfma_f32_16x16x32_bf16(aq0l_h, bkh0, z2, 0, 0, 0);
        z3 = __builtin_amdgcn_mfma_f32_16x16x32_bf16(aq0h_h, bkl0, z3, 0, 0, 0);
        z1 = __builtin_amdgcn_mfma_f32_16x16x32_bf16(aq1h_h, bkh1, z1, 0, 0, 0);
        z2 = __builtin_amdgcn_mfma_f32_16x16x32_bf16(aq1l_h, bkh1, z2, 0, 0, 0);
        z3 = __builtin_amdgcn_mfma_f32_16x16x32_bf16(aq1h_h, bkl1, z3, 0, 0, 0);
        sch[hh] = z1 + z2 + z3;
      }
      if (lact) {
        floatx4 z1 = {0.f, 0.f, 0.f, 0.f}, z2 = z1, z3 = z1;
        z1 = __builtin_amdgcn_mfma_f32_16x16x32_bf16(aq0h_l, bkh0, z1, 0, 0, 0);
        z2 = __builtin_amdgcn_mfma_f32_16x16x32_bf16(aq0l_l, bkh0, z2, 0, 0, 0);
        z3 = __builtin_amdgcn_mfma_f32_16x16x32_bf16(aq0h_l, bkl0, z3, 0, 0, 0);
        z1 = __builtin_amdgcn_mfma_f32_16x16x32_bf16(aq1h_l, bkh1, z1, 0, 0, 0);
        z2 = __builtin_amdgcn_mfma_f32_16x16x32_bf16(aq1l_l, bkh1, z2, 0, 0, 0);
        z3 = __builtin_amdgcn_mfma_f32_16x16x32_bf16(aq1h_l, bkl1, z3, 0, 0, 0);
        scl[hh] = z1 + z2 + z3;
      }
    }

    // ---- decay mask + row sums + stage P (both stripes), one fence ----
#pragma unroll
    for (int hh = 0; hh < 2; ++hh) {
      float cf = hh ? cf1 : cf0;
#pragma unroll
      for (int r = 0; r < 4; ++r) {
        int n = n0 + hh * 16 + l16;
        if (hact) {
          int m = m0h + quad * 4 + r;
          float p = (m >= n) ? sch[hh][r] * rfh[r] * cf : 0.f;
          rsh[r] += p;
          Plh[wave][(quad * 4 + r) * 32 + hh * 16 + l16] = f2b(p);
        }
        if (lact) {
          int m = m0l + quad * 4 + r;
          float p = (m >= n) ? scl[hh][r] * rfl[r] * cf : 0.f;
          rsl[r] += p;
          Pll[wave][(quad * 4 + r) * 32 + hh * 16 + l16] = f2b(p);
        }
      }
    }
#pragma unroll
    for (int r = 0; r < 4; ++r) {
      rfh[r] *= gstep;
      if (nt + 1 < lt_ntiles) rfl[r] *= gstep;
    }

    asm volatile("s_waitcnt lgkmcnt(0)" ::: "memory");
    bf16x8 pah, pal;
    if (hact) pah = *(const bf16x8*)&Plh[wave][l16 * 32 + quad * 8];
    if (lact) pal = *(const bf16x8*)&Pll[wave][l16 * 32 + quad * 8];

    // ---- PV for both stripes, sharing V fragments ----
#pragma unroll
    for (int dt = 0; dt < 8; ++dt) {
      int vrow = dt * 16 + l16;
      bf16x8 bv = *(const bf16x8*)&Vs[cur][vrow * 32 + ((quad + (vrow >> 1)) & 3) * 8];
      if (hact)
        oacch[dt] = __builtin_amdgcn_mfma_f32_16x16x32_bf16(pah, bv, oacch[dt], 0, 0, 0);
      if (lact)
        oaccl[dt] = __builtin_amdgcn_mfma_f32_16x16x32_bf16(pal, bv, oaccl[dt], 0, 0, 0);
    }
  }

  // ---- epilogue: denom clip, groupnorm(128), silu gate — per stripe ----
  auto finalize = [&](floatx4* oacc, float* rowsum, int m0) {
    float inv_den[4];
#pragma unroll
    for (int r = 0; r < 4; ++r) {
      float v = rowsum[r];
      v += __shfl_xor(v, 1);
      v += __shfl_xor(v, 2);
      v += __shfl_xor(v, 4);
      v += __shfl_xor(v, 8);
      inv_den[r] = 1.0f / fmaxf(fabsf(v), 1.0f);
    }
    float s1[4] = {}, s2[4] = {};
#pragma unroll
    for (int dt = 0; dt < 8; ++dt) {
#pragma unroll
      for (int r = 0; r < 4; ++r) {
        float v = oacc[dt][r] * inv_den[r];
        oacc[dt][r] = v;
        s1[r] += v;
        s2[r] += v * v;
      }
    }
    float mean[4], istd[4];
#pragma unroll
    for (int r = 0; r < 4; ++r) {
      float a = s1[r], q2 = s2[r];
      a += __shfl_xor(a, 1); a += __shfl_xor(a, 2);
      a += __shfl_xor(a, 4); a += __shfl_xor(a, 8);
      q2 += __shfl_xor(q2, 1); q2 += __shfl_xor(q2, 2);
      q2 += __shfl_xor(q2, 4); q2 += __shfl_xor(q2, 8);
      mean[r] = a * (1.0f / 128.0f);
      float var = q2 * (1.0f / 128.0f) - mean[r] * mean[r];
      istd[r] = rsqrtf(fmaxf(var, 0.0f) + 1e-5f);
    }
#pragma unroll
    for (int dt = 0; dt < 8; ++dt) {
#pragma unroll
      for (int r = 0; r < 4; ++r) {
        int m = m0 + quad * 4 + r;
        int col = h * HD + dt * 16 + l16;
        float v = (oacc[dt][r] - mean[r]) * istd[r];
        float gv = g[((size_t)b * SEQ + m) * 2048 + col];
        float sg = gv / (1.0f + expf(-gv));
        gated[((size_t)b * SEQ + m) * 2048 + col] = f2b(sg * v);
      }
    }
  };
  finalize(oacch, rsh, m0h);
  finalize(oaccl, rsl, m0l);
}

// ---------------- launch ----------------
extern "C" void kernel_launch(void* const* d_in, const int* in_sizes, int n_in,
                              void* d_out, int out_size, void* d_ws,
                              size_t ws_size, hipStream_t stream) {
  const float* x   = (const float*)d_in[0];
  const float* q_w = (const float*)d_in[1];
  const float* q_b = (const float*)d_in[2];
  const float* k_w = (const float*)d_in[3];
  const float* k_b = (const float*)d_in[4];
  const float* v_w = (const float*)d_in[5];
  const float* v_b = (const float*)d_in[6];
  const float* g_w = (const float*)d_in[7];
  const float* g_b = (const float*)d_in[8];
  const float* o_w = (const float*)d_in[9];
  const float* o_b = (const float*)d_in[10];

  char* ws = (char*)d_ws;
  bf16* Wt    = (bf16*)ws; ws += (size_t)6144 * 1024 * 2;
  bf16* oT    = (bf16*)ws; ws += (size_t)1024 * 2048 * 2;
  bf16* xb    = (bf16*)ws; ws += (size_t)4096 * 1024 * 2;
  float* Cqk  = (float*)ws; ws += (size_t)4096 * 2048 * 4;
  bf16* qhb   = (bf16*)ws; ws += (size_t)32 * 2048 * 64 * 2;
  bf16* qlb   = (bf16*)ws; ws += (size_t)32 * 2048 * 64 * 2;
  bf16* khb   = (bf16*)ws; ws += (size_t)32 * 2048 * 64 * 2;
  bf16* klb   = (bf16*)ws; ws += (size_t)32 * 2048 * 64 * 2;
  bf16* vTb   = (bf16*)ws; ws += (size_t)32 * 128 * 2048 * 2;
  float* gbuf = (float*)ws; ws += (size_t)2 * 2048 * 2048 * 4;
  bf16* gated = (bf16*)ws; ws += (size_t)4096 * 2048 * 2;
  // vbuf aliases gated: vbuf lives GEMM1->vtrans, gated lives retention->GEMM2
  bf16* vbuf  = gated;

  convert_k<<<(4096 * 1024 / 4) / 256, 256, 0, stream>>>(x, xb);

  dim3 tb(32, 8);
  transpose_k<<<dim3(1024 / 32, 1024 / 32), tb, 0, stream>>>(q_w, Wt, 1024, 1024);
  transpose_k<<<dim3(1024 / 32, 1024 / 32), tb, 0, stream>>>(k_w, Wt + (size_t)1024 * 1024, 1024, 1024);
  transpose_k<<<dim3(2048 / 32, 1024 / 32), tb, 0, stream>>>(v_w, Wt + (size_t)2048 * 1024, 1024, 2048);
  transpose_k<<<dim3(2048 / 32, 1024 / 32), tb, 0, stream>>>(g_w, Wt + (size_t)4096 * 1024, 1024, 2048);
  transpose_k<<<dim3(1024 / 32, 2048 / 32), tb, 0, stream>>>(o_w, oT, 2048, 1024);

  gemm_bt<128, 128, 1024, 0><<<dim3(6144 / 128, 4096 / 128), 256, 0, stream>>>(
      xb, Wt, 6144, q_b, k_b, v_b, g_b, Cqk, vbuf, gbuf, nullptr);

  vtrans_k<<<dim3(64, 64, B_SZ), tb, 0, stream>>>(vbuf, vTb);

  router_k<<<(4096 * 1024) / 256, 256, 0, stream>>>(Cqk, qhb, qlb, khb, klb);

  retention_k<<<dim3(1024), 128, 0, stream>>>(
      qhb, qlb, khb, klb, vTb, gbuf, gated);

  gemm_bt<128, 64, 2048, 1><<<dim3(1024 / 64, 4096 / 128), 256, 0, stream>>>(
      gated, oT, 1024, o_b, nullptr, nullptr, nullptr, nullptr, nullptr,
      nullptr, (float*)d_out);
}

// Round 2
// 352.359 us; speedup vs baseline: 1.0375x; 1.0375x over previous
//
#include <hip/hip_runtime.h>
#include <hip/hip_bf16.h>

// MultiScaleRetention forward. Inputs/outputs FLOAT32; internals bf16 MFMA.
//   0) convert x -> xb (bf16); transpose weights f32 -> bf16
//   1) GEMM1 (m97-style, global_load_lds staging): xb @ Wt^T; LEAN epilogue,
//      ALL-COALESCED: qk -> f32 Cqk (+bias,+k-scale); v -> bf16 vbuf; g -> f32
//   2) vtrans: vbuf (b, s, 2048) -> vT (bh, 128, S)
//   3) router: rotary (f32) + hi/lo bf16 split + (bh,S,64) layout for q,k
//   4) retention: R12 = R11 pairing + SWAPPED QK^T (mfma(K,Q)) so the score
//      tile is transposed (lane: m=l16, n=quad*4+r). P->bf16 pack +
//      v_permlane32_swap_b32 + v_permlane16_swap_b32 rebuild the PV
//      A-fragment IN-REGISTER. This deletes the P LDS round trip (16 scalar
//      ds_write_b16 + 2 ds_read_b128 + lgkmcnt(0) drain per iter) that sat on
//      the critical path (R11 counters: no pipe >32% busy, ~6.5K cyc/iter
//      wall vs ~800 cyc chain -> serialization-bound, not TLP-bound).
//      rf/rs become per-lane scalars (m=l16). Row-sum reduce: xor16+xor32,
//      then shfl to (quad*4+r) layout for the epilogue.
//   5) GEMM2: gated @ oT^T + o_b -> d_out (f32)
//
// Per-element P math bit-identical; row-sum order changes (low-order bits).

typedef __hip_bfloat16 bf16;
typedef short bf16x4 __attribute__((ext_vector_type(4)));
typedef short bf16x8 __attribute__((ext_vector_type(8)));
typedef float floatx4 __attribute__((ext_vector_type(4)));

#define B_SZ 2
#define SEQ 2048
#define NH 16
#define KD 64
#define HD 128

// global->LDS direct copy, 16B/lane. LDS dest is wave-uniform base + lane*16.
#define ASYNC16(gp, lp)                                                             \
  __builtin_amdgcn_global_load_lds(                                                 \
      (const __attribute__((address_space(1))) unsigned int*)(unsigned long long)(const void*)(gp), \
      (__attribute__((address_space(3))) unsigned int*)(unsigned int)(unsigned long long)(void*)(lp), \
      16, 0, 0)

__device__ __forceinline__ float b2f(bf16 x) { return __bfloat162float(x); }
__device__ __forceinline__ bf16 f2b(float x) { return __float2bfloat16(x); }

// ---------------- f32 -> bf16 convert (x) ----------------
__global__ void convert_k(const float* __restrict__ in, bf16* __restrict__ out) {
  int i = blockIdx.x * 256 + threadIdx.x;  // one float4 per thread
  float4 v = reinterpret_cast<const float4*>(in)[i];
  union { bf16 h[4]; bf16x4 v4; } u;
  u.h[0] = f2b(v.x); u.h[1] = f2b(v.y); u.h[2] = f2b(v.z); u.h[3] = f2b(v.w);
  reinterpret_cast<bf16x4*>(out)[i] = u.v4;
}

// ---------------- weight transpose: in f32 (K,N) -> out bf16 (N,K) --------
__global__ void transpose_k(const float* __restrict__ in, bf16* __restrict__ out,
                            int K, int N) {
  __shared__ float tile[32][33];
  int tx = threadIdx.x, ty = threadIdx.y;
  int n0 = blockIdx.x * 32, k0 = blockIdx.y * 32;
#pragma unroll
  for (int j = 0; j < 4; ++j)
    tile[ty + j * 8][tx] = in[(size_t)(k0 + ty + j * 8) * N + n0 + tx];
  __syncthreads();
#pragma unroll
  for (int j = 0; j < 4; ++j)
    out[(size_t)(n0 + ty + j * 8) * K + k0 + tx] = f2b(tile[tx][ty + j * 8]);
}

// ---------------- v transpose: per-b 2048x2048 bf16 ----------------
__global__ void vtrans_k(const bf16* __restrict__ in, bf16* __restrict__ out) {
  __shared__ bf16 tile[32][34];
  int tx = threadIdx.x, ty = threadIdx.y;
  int s0 = blockIdx.x * 32, c0 = blockIdx.y * 32;
  const bf16* src = in + (size_t)blockIdx.z * 2048 * 2048;
  bf16* dst = out + (size_t)blockIdx.z * 2048 * 2048;
#pragma unroll
  for (int j = 0; j < 4; ++j)
    tile[ty + j * 8][tx] = src[(size_t)(s0 + ty + j * 8) * 2048 + c0 + tx];
  __syncthreads();
#pragma unroll
  for (int j = 0; j < 4; ++j)
    dst[(size_t)(c0 + ty + j * 8) * 2048 + s0 + tx] = tile[tx][ty + j * 8];
}

// ---------------- GEMM: C(M,N) = A(M,K) @ Bt(N,K)^T ----------------
template <int BM, int BN, int KDIM, int MODE>
__global__ __launch_bounds__(256, 2) void gemm_bt(
    const bf16* __restrict__ A, const bf16* __restrict__ Bt, int Ndim,
    const float* __restrict__ bias_q, const float* __restrict__ bias_k,
    const float* __restrict__ bias_v, const float* __restrict__ bias_g,
    float* __restrict__ outCqk, bf16* __restrict__ out_v,
    float* __restrict__ out_g, float* __restrict__ outF) {
  __shared__ bf16 As[BM * 32];
  __shared__ bf16 Bs[BN * 32];
  const int tid = threadIdx.x;
  const int wave = tid >> 6, lane = tid & 63;
  const int quad = lane >> 4, l16 = lane & 15;
  const int m0 = blockIdx.y * BM, n0 = blockIdx.x * BN;
  constexpr int FI = BM / 32;
  constexpr int FJ = BN / 32;
  const int wm = (wave >> 1) * (BM / 2), wn = (wave & 1) * (BN / 2);

  floatx4 acc[FI][FJ] = {};

  for (int k0 = 0; k0 < KDIM; k0 += 32) {
#pragma unroll
    for (int j = 0; j < BM / 64; ++j) {
      int cbase = (j * 4 + wave) * 64;
      int c = cbase + lane;
      const bf16* g = A + (size_t)(m0 + (c >> 2)) * KDIM + k0 + (c & 3) * 8;
      ASYNC16(g, &As[cbase * 8]);
    }
#pragma unroll
    for (int j = 0; j < BN / 64; ++j) {
      int cbase = (j * 4 + wave) * 64;
      int c = cbase + lane;
      const bf16* g = Bt + (size_t)(n0 + (c >> 2)) * KDIM + k0 + (c & 3) * 8;
      ASYNC16(g, &Bs[cbase * 8]);
    }
    __syncthreads();  // compiler drains vmcnt(0) before s_barrier

    bf16x8 af[FI], bfr[FJ];
#pragma unroll
    for (int i = 0; i < FI; ++i)
      af[i] = *(const bf16x8*)&As[(wm + i * 16 + l16) * 32 + quad * 8];
#pragma unroll
    for (int j = 0; j < FJ; ++j)
      bfr[j] = *(const bf16x8*)&Bs[(wn + j * 16 + l16) * 32 + quad * 8];
#pragma unroll
    for (int i = 0; i < FI; ++i)
#pragma unroll
      for (int j = 0; j < FJ; ++j)
        acc[i][j] = __builtin_amdgcn_mfma_f32_16x16x32_bf16(af[i], bfr[j],
                                                            acc[i][j], 0, 0, 0);
    __syncthreads();
  }

  // LEAN epilogue, all stores coalesced
#pragma unroll
  for (int i = 0; i < FI; ++i) {
#pragma unroll
    for (int j = 0; j < FJ; ++j) {
#pragma unroll
      for (int r = 0; r < 4; ++r) {
        int gm = m0 + wm + i * 16 + quad * 4 + r;
        int gn = n0 + wn + j * 16 + l16;
        float v = acc[i][j][r];
        if (MODE == 1) {
          v += bias_q[gn];  // bias_q = o_b
          outF[(size_t)gm * Ndim + gn] = v;
        } else {
          if (gn < 2048) {
            bool is_k = gn >= 1024;
            int jj = is_k ? gn - 1024 : gn;
            v += is_k ? bias_k[jj] : bias_q[jj];
            if (is_k) v *= 0.125f;  // SCALING = KEY_DIM^-0.5
            outCqk[(size_t)gm * 2048 + gn] = v;  // f32, exact
          } else if (gn < 4096) {
            int jj = gn - 2048;
            v += bias_v[jj];
            out_v[(size_t)gm * 2048 + jj] = f2b(v);  // natural layout
          } else {
            int jj = gn - 4096;
            v += bias_g[jj];
            out_g[(size_t)gm * 2048 + jj] = v;  // f32
          }
        }
      }
    }
  }
}

// ---------------- router: rotary + hi/lo split + layout ----------------
__global__ void router_k(const float* __restrict__ Cqk,
                         bf16* __restrict__ qh, bf16* __restrict__ ql,
                         bf16* __restrict__ kh, bf16* __restrict__ kl) {
  int t = blockIdx.x * 256 + threadIdx.x;  // 4096*1024 threads
  int row = t >> 10, pc = t & 1023;
  int b = row >> 11, s = row & 2047;
  bool is_k = pc >= 512;
  int jj = (pc - (is_k ? 512 : 0)) * 2;  // even, 0..1022
  int h = jj >> 6, d = jj & 63, ii = d >> 1;
  float2 v = *(const float2*)&Cqk[(size_t)row * 2048 + pc * 2];
  float half = exp2f(-(float)ii * (13.287712379549449f / 31.0f));
  float ang = (float)s * half;
  float sn = sinf(ang), cs = cosf(ang);
  float e = v.x * cs - v.y * sn;
  float o = v.y * cs + v.x * sn;
  bf16 eh = f2b(e), oh = f2b(o);
  bf16 el = f2b(e - b2f(eh)), ol = f2b(o - b2f(oh));
  size_t idx = (((size_t)b * NH + h) * SEQ + s) * KD + d;
  bf16* ph = is_k ? kh : qh;
  bf16* pl = is_k ? kl : ql;
  union { bf16 h2[2]; unsigned u; } uh, ul;
  uh.h2[0] = eh; uh.h2[1] = oh;
  ul.h2[0] = el; ul.h2[1] = ol;
  *(unsigned*)&ph[idx] = uh.u;
  *(unsigned*)&pl[idx] = ul.u;
}

// ---------------- retention core (R12: swapped QK + permlane P) ----------
// grid 1024 flat; bid -> (seg = bid>>5 -> h=seg&15, b=seg>>4), px_raw=bid&31.
// px = (seg bit3) ? 31-px_raw : px_raw  -> co-resident blocks (bid+256) get
// complementary px so each CU's 4 blocks total a uniform 194 iterations.
// Block px owns TWO 32-row half-stripes: heavy bt_h=63-px, light bt_l=px.
// QK computed SWAPPED (A=K-frag, B=Q-frag): score lane layout m=l16 (fixed),
// n=quad*4+r per 16-col half -> P stays in-register; permlane32/16_swap
// rebuild the PV A-fragment. No P LDS traffic, no mid-iteration lgkm drain.
__global__ __launch_bounds__(128, 2) void retention_k(
    const bf16* __restrict__ qh, const bf16* __restrict__ ql,
    const bf16* __restrict__ kh, const bf16* __restrict__ kl,
    const bf16* __restrict__ vT, const float* __restrict__ g,
    bf16* __restrict__ gated) {
  __shared__ bf16 KHs[2][32 * 64];
  __shared__ bf16 KLs[2][32 * 64];
  __shared__ bf16 Vs[2][128 * 32];
  const int tid = threadIdx.x;
  const int wave = tid >> 6, lane = tid & 63;
  const int quad = lane >> 4, l16 = lane & 15;
  const int bid = blockIdx.x;
  const int px_raw = bid & 31;
  const int seg = bid >> 5;           // 0..31
  const int h = seg & 15, b = seg >> 4;
  const int px = ((seg >> 3) & 1) ? (31 - px_raw) : px_raw;
  const int bh = b * NH + h;
  const int bt_h = 63 - px;           // heavy half-stripe (32 rows)
  const int bt_l = px;                // light half-stripe
  const int m0h = bt_h * 32 + wave * 16;
  const int m0l = bt_l * 32 + wave * 16;
  const int ntiles = bt_h + 1;
  const int lt_ntiles = bt_l + 1;

  const float t = exp2f(-(float)(5 + h));  // 1-gamma (exact)
  const float lng = log1pf(-t);            // ln(gamma)
  const float log2g = lng * 1.44269504088896340736f;

  // per-lane row scalars (m = m0 + l16)
  float rfh, rfl;
  {
    int mh = m0h + l16, ml = m0l + l16;
    rfh = exp2f((float)mh * log2g) *
          rsqrtf(-expm1f((float)(mh + 1) * lng) / t);
    rfl = exp2f((float)ml * log2g) *
          rsqrtf(-expm1f((float)(ml + 1) * lng) / t);
  }
  const float gstep = exp2f(-32.0f * log2g);  // gamma^-32
  // per-lane col decay: n-offset = hh*16 + quad*4 + r
  float cfq[8];
#pragma unroll
  for (int i = 0; i < 8; ++i) {
    int hh = i >> 2, r = i & 3;
    cfq[i] = exp2f(-(float)(hh * 16 + quad * 4 + r) * log2g);
  }

  const size_t qoffh = ((size_t)bh * SEQ + m0h + l16) * KD;
  const size_t qoffl = ((size_t)bh * SEQ + m0l + l16) * KD;
  bf16x8 aq0h_h = *(const bf16x8*)&qh[qoffh + quad * 8];
  bf16x8 aq1h_h = *(const bf16x8*)&qh[qoffh + 32 + quad * 8];
  bf16x8 aq0l_h = *(const bf16x8*)&ql[qoffh + quad * 8];
  bf16x8 aq1l_h = *(const bf16x8*)&ql[qoffh + 32 + quad * 8];
  bf16x8 aq0h_l = *(const bf16x8*)&qh[qoffl + quad * 8];
  bf16x8 aq1h_l = *(const bf16x8*)&qh[qoffl + 32 + quad * 8];
  bf16x8 aq0l_l = *(const bf16x8*)&ql[qoffl + quad * 8];
  bf16x8 aq1l_l = *(const bf16x8*)&ql[qoffl + 32 + quad * 8];

  floatx4 oacch[8] = {}, oaccl[8] = {};
  float rsh = 0.f, rsl = 0.f;

  const bf16* khb = kh + (size_t)bh * SEQ * KD;
  const bf16* klb = kl + (size_t)bh * SEQ * KD;
  const bf16* vbase = vT + (size_t)bh * HD * SEQ;

  // 16 x 1KB chunks per tile, split over 2 waves: wave0 -> K (hi+lo),
  // wave1 -> V. Same swizzled layouts as R10/R11.
  auto stage = [&](int nt, int buf) {
    const int n0s = nt * 32;
#pragma unroll
    for (int j = 0; j < 8; ++j) {
      int cc = wave * 8 + j;
      if (cc < 8) {
        const bf16* src = (cc < 4) ? khb : klb;
        bf16* dst = (cc < 4) ? KHs[buf] : KLs[buf];
        int r = ((cc & 3) * 8) + (lane >> 3);
        int s = lane & 7;
        int q = (s - r) & 7;
        ASYNC16(src + (size_t)(n0s + r) * KD + q * 8, &dst[(cc & 3) * 512]);
      } else {
        int r = (cc - 8) * 16 + (lane >> 2);
        int s = lane & 3;
        int q = (s - (r >> 1)) & 3;
        ASYNC16(vbase + (size_t)r * SEQ + n0s + q * 8, &Vs[buf][(cc - 8) * 512]);
      }
    }
  };

  // Build PV A-frag in-register from the transposed score tile.
  // sc[hh][r] holds S[n=quad*4+r (+hh*16)][m=l16]. After pack+swaps, lane
  // (quad Q, l16=m) holds P[m][8Q..8Q+7] as bf16x8.
  auto buildPA = [&](const floatx4* sc, float rf, float& rs, int n0,
                     int m0) -> bf16x8 {
    const int m = m0 + l16;
    const bool full = (m0 >= n0 + 31);  // tile fully below diagonal
    unsigned d[4];
#pragma unroll
    for (int hh = 0; hh < 2; ++hh) {
      float p[4];
#pragma unroll
      for (int r = 0; r < 4; ++r) {
        float pv;
        if (full) {
          pv = sc[hh][r] * rf * cfq[hh * 4 + r];
        } else {
          int n = n0 + hh * 16 + quad * 4 + r;
          pv = (m >= n) ? sc[hh][r] * rf * cfq[hh * 4 + r] : 0.f;
        }
        rs += pv;
        p[r] = pv;
      }
      union { bf16 hx[2]; unsigned u; } u0, u1;
      u0.hx[0] = f2b(p[0]); u0.hx[1] = f2b(p[1]);
      u1.hx[0] = f2b(p[2]); u1.hx[1] = f2b(p[3]);
      d[hh * 2 + 0] = u0.u;
      d[hh * 2 + 1] = u1.u;
    }
    unsigned a0 = d[0], b0 = d[2];  // (hh0 pair01, hh1 pair01)
    asm("v_permlane32_swap_b32 %0, %1" : "+v"(a0), "+v"(b0));
    asm("v_permlane16_swap_b32 %0, %1" : "+v"(a0), "+v"(b0));
    unsigned a1 = d[1], b1 = d[3];  // (hh0 pair23, hh1 pair23)
    asm("v_permlane32_swap_b32 %0, %1" : "+v"(a1), "+v"(b1));
    asm("v_permlane16_swap_b32 %0, %1" : "+v"(a1), "+v"(b1));
    union { unsigned u[4]; bf16x8 v; } pu;
    pu.u[0] = a0; pu.u[1] = a1; pu.u[2] = b0; pu.u[3] = b1;
    return pu.v;
  };

  stage(0, 0);
  for (int nt = 0; nt < ntiles; ++nt) {
    const int n0 = nt * 32;
    const int cur = nt & 1;
    asm volatile("s_waitcnt vmcnt(0) lgkmcnt(0)" ::: "memory");
    __syncthreads();
    {
      int pf = (nt + 1 < ntiles) ? nt + 1 : nt;
      stage(pf, cur ^ 1);
    }

    const bool hact = (n0 <= m0h + 15);
    const bool lact = (n0 <= m0l + 15);

    // ---- QK (SWAPPED: A=K-frag, B=Q-frag) for both stripes, sharing K ----
    floatx4 sch[2], scl[2];
#pragma unroll
    for (int hh = 0; hh < 2; ++hh) {
      int krow = hh * 16 + l16;
      int c0 = ((quad + krow) & 7) * 8;
      int c1 = ((quad + 4 + krow) & 7) * 8;
      bf16x8 bkh0 = *(const bf16x8*)&KHs[cur][krow * 64 + c0];
      bf16x8 bkh1 = *(const bf16x8*)&KHs[cur][krow * 64 + c1];
      bf16x8 bkl0 = *(const bf16x8*)&KLs[cur][krow * 64 + c0];
      bf16x8 bkl1 = *(const bf16x8*)&KLs[cur][krow * 64 + c1];
      if (hact) {
        floatx4 z1 = {0.f, 0.f, 0.f, 0.f}, z2 = z1, z3 = z1;
        z1 = __builtin_amdgcn_mfma_f32_16x16x32_bf16(bkh0, aq0h_h, z1, 0, 0, 0);
        z2 = __builtin_amdgcn_mfma_f32_16x16x32_bf16(bkh0, aq0l_h, z2, 0, 0, 0);
        z3 = __builtin_amdgcn_mfma_f32_16x16x32_bf16(bkl0, aq0h_h, z3, 0, 0, 0);
        z1 = __builtin_amdgcn_mfma_f32_16x16x32_bf16(bkh1, aq1h_h, z1, 0, 0, 0);
        z2 = __builtin_amdgcn_mfma_f32_16x16x32_bf16(bkh1, aq1l_h, z2, 0, 0, 0);
        z3 = __builtin_amdgcn_mfma_f32_16x16x32_bf16(bkl1, aq1h_h, z3, 0, 0, 0);
        sch[0 + hh] = z1 + z2 + z3;
      }
      if (lact) {
        floatx4 z1 = {0.f, 0.f, 0.f, 0.f}, z2 = z1, z3 = z1;
        z1 = __builtin_amdgcn_mfma_f32_16x16x32_bf16(bkh0, aq0h_l, z1, 0, 0, 0);
        z2 = __builtin_amdgcn_mfma_f32_16x16x32_bf16(bkh0, aq0l_l, z2, 0, 0, 0);
        z3 = __builtin_amdgcn_mfma_f32_16x16x32_bf16(bkl0, aq0h_l, z3, 0, 0, 0);
        z1 = __builtin_amdgcn_mfma_f32_16x16x32_bf16(bkh1, aq1h_l, z1, 0, 0, 0);
        z2 = __builtin_amdgcn_mfma_f32_16x16x32_bf16(bkh1, aq1l_l, z2, 0, 0, 0);
        z3 = __builtin_amdgcn_mfma_f32_16x16x32_bf16(bkl1, aq1h_l, z3, 0, 0, 0);
        scl[0 + hh] = z1 + z2 + z3;
      }
    }

    // ---- decay mask + row sums + PA rebuild, all in-register ----
    bf16x8 pah, pal;
    if (hact) pah = buildPA(sch, rfh, rsh, n0, m0h);
    if (lact) pal = buildPA(scl, rfl, rsl, n0, m0l);
    rfh *= gstep;
    if (nt + 1 < lt_ntiles) rfl *= gstep;

    // ---- PV for both stripes, sharing V fragments ----
#pragma unroll
    for (int dt = 0; dt < 8; ++dt) {
      int vrow = dt * 16 + l16;
      bf16x8 bv = *(const bf16x8*)&Vs[cur][vrow * 32 + ((quad + (vrow >> 1)) & 3) * 8];
      if (hact)
        oacch[dt] = __builtin_amdgcn_mfma_f32_16x16x32_bf16(pah, bv, oacch[dt], 0, 0, 0);
      if (lact)
        oaccl[dt] = __builtin_amdgcn_mfma_f32_16x16x32_bf16(pal, bv, oaccl[dt], 0, 0, 0);
    }
  }

  // ---- epilogue: denom clip, groupnorm(128), silu gate — per stripe ----
  // rowsum is per-lane (row m0+l16); reduce across quads, then shuffle to
  // the oacc layout (row = quad*4+r).
  auto finalize = [&](floatx4* oacc, float rowsum, int m0) {
    float v = rowsum;
    v += __shfl_xor(v, 16);
    v += __shfl_xor(v, 32);
    float inv_den[4];
#pragma unroll
    for (int r = 0; r < 4; ++r) {
      float dsum = __shfl(v, quad * 4 + r);
      inv_den[r] = 1.0f / fmaxf(fabsf(dsum), 1.0f);
    }
    float s1[4] = {}, s2[4] = {};
#pragma unroll
    for (int dt = 0; dt < 8; ++dt) {
#pragma unroll
      for (int r = 0; r < 4; ++r) {
        float vv = oacc[dt][r] * inv_den[r];
        oacc[dt][r] = vv;
        s1[r] += vv;
        s2[r] += vv * vv;
      }
    }
    float mean[4], istd[4];
#pragma unroll
    for (int r = 0; r < 4; ++r) {
      float a = s1[r], q2 = s2[r];
      a += __shfl_xor(a, 1); a += __shfl_xor(a, 2);
      a += __shfl_xor(a, 4); a += __shfl_xor(a, 8);
      q2 += __shfl_xor(q2, 1); q2 += __shfl_xor(q2, 2);
      q2 += __shfl_xor(q2, 4); q2 += __shfl_xor(q2, 8);
      mean[r] = a * (1.0f / 128.0f);
      float var = q2 * (1.0f / 128.0f) - mean[r] * mean[r];
      istd[r] = rsqrtf(fmaxf(var, 0.0f) + 1e-5f);
    }
#pragma unroll
    for (int dt = 0; dt < 8; ++dt) {
#pragma unroll
      for (int r = 0; r < 4; ++r) {
        int m = m0 + quad * 4 + r;
        int col = h * HD + dt * 16 + l16;
        float vv = (oacc[dt][r] - mean[r]) * istd[r];
        float gv = g[((size_t)b * SEQ + m) * 2048 + col];
        float sg = gv / (1.0f + expf(-gv));
        gated[((size_t)b * SEQ + m) * 2048 + col] = f2b(sg * vv);
      }
    }
  };
  finalize(oacch, rsh, m0h);
  finalize(oaccl, rsl, m0l);
}

// ---------------- launch ----------------
extern "C" void kernel_launch(void* const* d_in, const int* in_sizes, int n_in,
                              void* d_out, int out_size, void* d_ws,
                              size_t ws_size, hipStream_t stream) {
  const float* x   = (const float*)d_in[0];
  const float* q_w = (const float*)d_in[1];
  const float* q_b = (const float*)d_in[2];
  const float* k_w = (const float*)d_in[3];
  const float* k_b = (const float*)d_in[4];
  const float* v_w = (const float*)d_in[5];
  const float* v_b = (const float*)d_in[6];
  const float* g_w = (const float*)d_in[7];
  const float* g_b = (const float*)d_in[8];
  const float* o_w = (const float*)d_in[9];
  const float* o_b = (const float*)d_in[10];

  char* ws = (char*)d_ws;
  bf16* Wt    = (bf16*)ws; ws += (size_t)6144 * 1024 * 2;
  bf16* oT    = (bf16*)ws; ws += (size_t)1024 * 2048 * 2;
  bf16* xb    = (bf16*)ws; ws += (size_t)4096 * 1024 * 2;
  float* Cqk  = (float*)ws; ws += (size_t)4096 * 2048 * 4;
  bf16* qhb   = (bf16*)ws; ws += (size_t)32 * 2048 * 64 * 2;
  bf16* qlb   = (bf16*)ws; ws += (size_t)32 * 2048 * 64 * 2;
  bf16* khb   = (bf16*)ws; ws += (size_t)32 * 2048 * 64 * 2;
  bf16* klb   = (bf16*)ws; ws += (size_t)32 * 2048 * 64 * 2;
  bf16* vTb   = (bf16*)ws; ws += (size_t)32 * 128 * 2048 * 2;
  float* gbuf = (float*)ws; ws += (size_t)2 * 2048 * 2048 * 4;
  bf16* gated = (bf16*)ws; ws += (size_t)4096 * 2048 * 2;
  // vbuf aliases gated: vbuf lives GEMM1->vtrans, gated lives retention->GEMM2
  bf16* vbuf  = gated;

  convert_k<<<(4096 * 1024 / 4) / 256, 256, 0, stream>>>(x, xb);

  dim3 tb(32, 8);
  transpose_k<<<dim3(1024 / 32, 1024 / 32), tb, 0, stream>>>(q_w, Wt, 1024, 1024);
  transpose_k<<<dim3(1024 / 32, 1024 / 32), tb, 0, stream>>>(k_w, Wt + (size_t)1024 * 1024, 1024, 1024);
  transpose_k<<<dim3(2048 / 32, 1024 / 32), tb, 0, stream>>>(v_w, Wt + (size_t)2048 * 1024, 1024, 2048);
  transpose_k<<<dim3(2048 / 32, 1024 / 32), tb, 0, stream>>>(g_w, Wt + (size_t)4096 * 1024, 1024, 2048);
  transpose_k<<<dim3(1024 / 32, 2048 / 32), tb, 0, stream>>>(o_w, oT, 2048, 1024);

  gemm_bt<128, 128, 1024, 0><<<dim3(6144 / 128, 4096 / 128), 256, 0, stream>>>(
      xb, Wt, 6144, q_b, k_b, v_b, g_b, Cqk, vbuf, gbuf, nullptr);

  vtrans_k<<<dim3(64, 64, B_SZ), tb, 0, stream>>>(vbuf, vTb);

  router_k<<<(4096 * 1024) / 256, 256, 0, stream>>>(Cqk, qhb, qlb, khb, klb);

  retention_k<<<dim3(1024), 128, 0, stream>>>(
      qhb, qlb, khb, klb, vTb, gbuf, gated);

  gemm_bt<128, 64, 2048, 1><<<dim3(1024 / 64, 4096 / 128), 256, 0, stream>>>(
      gated, oT, 1024, o_b, nullptr, nullptr, nullptr, nullptr, nullptr,
      nullptr, (float*)d_out);
}

// Round 5
// 341.261 us; speedup vs baseline: 1.0712x; 1.0325x over previous
//
#include <hip/hip_runtime.h>
#include <hip/hip_bf16.h>

// MultiScaleRetention forward. Inputs/outputs FLOAT32; internals bf16 MFMA.
//   0) convert x -> xb (bf16); transpose weights f32 -> bf16
//   1) GEMM1 (m97-style, global_load_lds staging): xb @ Wt^T; LEAN epilogue,
//      ALL-COALESCED: qk -> f32 Cqk (+bias,+k-scale); v -> bf16 vbuf; g -> f32
//   2) vtrans: vbuf (b, s, 2048) -> vf FRAGMENT layout [bh][nt][dt][lane]x16B
//   3) router: rotary (f32) + hi/lo bf16 split + (bh,S,64) layout for q,k
//      (R12 version, unchanged)
//   4) retention R15 = R12 retention (LDS-staged K hi/lo, paired 32-row
//      half-stripes, swapped QK + permlane P) with ONE delta: V is loaded
//      DIRECTLY global->registers from the fragment-ordered vf buffer
//      (8 coalesced global_load_dwordx4 per tile, issued after the barrier;
//      compiler's counted vmcnt hides them under QK/buildPA and keeps the 4
//      K-staging loads in flight). Removes Vs LDS (32->16 KB), halves staged
//      bytes and the top-of-iter vmcnt drain, cuts 8 ds_read_b128/wave/iter.
//      PV operand VALUES are bit-identical to R12 -> absmax must be exactly
//      0.01049805 (canary). This also bisects R13/R14's NaN: K-fragment path
//      and zero-barrier loop are NOT included here; only the V-fragment path
//      is new. R13/R14 post-mortem: workspace theory disproved (R14 footprint
//      142.6MB < R12's 159.4MB envelope, still NaN) -> bug is in the R13 code
//      itself; bisect instead of blind iteration.
//   5) GEMM2: gated @ oT^T + o_b -> d_out (f32)

typedef __hip_bfloat16 bf16;
typedef short bf16x4 __attribute__((ext_vector_type(4)));
typedef short bf16x8 __attribute__((ext_vector_type(8)));
typedef float floatx4 __attribute__((ext_vector_type(4)));

#define B_SZ 2
#define SEQ 2048
#define NH 16
#define KD 64
#define HD 128

// global->LDS direct copy, 16B/lane. LDS dest is wave-uniform base + lane*16.
#define ASYNC16(gp, lp)                                                             \
  __builtin_amdgcn_global_load_lds(                                                 \
      (const __attribute__((address_space(1))) unsigned int*)(unsigned long long)(const void*)(gp), \
      (__attribute__((address_space(3))) unsigned int*)(unsigned int)(unsigned long long)(void*)(lp), \
      16, 0, 0)

__device__ __forceinline__ float b2f(bf16 x) { return __bfloat162float(x); }
__device__ __forceinline__ bf16 f2b(float x) { return __float2bfloat16(x); }

#define MFMA16(a, bb, c) __builtin_amdgcn_mfma_f32_16x16x32_bf16(a, bb, c, 0, 0, 0)

// ---------------- f32 -> bf16 convert (x) ----------------
__global__ void convert_k(const float* __restrict__ in, bf16* __restrict__ out) {
  int i = blockIdx.x * 256 + threadIdx.x;  // one float4 per thread
  float4 v = reinterpret_cast<const float4*>(in)[i];
  union { bf16 h[4]; bf16x4 v4; } u;
  u.h[0] = f2b(v.x); u.h[1] = f2b(v.y); u.h[2] = f2b(v.z); u.h[3] = f2b(v.w);
  reinterpret_cast<bf16x4*>(out)[i] = u.v4;
}

// ---------------- weight transpose: in f32 (K,N) -> out bf16 (N,K) --------
__global__ void transpose_k(const float* __restrict__ in, bf16* __restrict__ out,
                            int K, int N) {
  __shared__ float tile[32][33];
  int tx = threadIdx.x, ty = threadIdx.y;
  int n0 = blockIdx.x * 32, k0 = blockIdx.y * 32;
#pragma unroll
  for (int j = 0; j < 4; ++j)
    tile[ty + j * 8][tx] = in[(size_t)(k0 + ty + j * 8) * N + n0 + tx];
  __syncthreads();
#pragma unroll
  for (int j = 0; j < 4; ++j)
    out[(size_t)(n0 + ty + j * 8) * K + k0 + tx] = f2b(tile[tx][ty + j * 8]);
}

// ---------------- v transpose -> V fragment layout ----------------
// out element for PV B-frag: chunk = (bh*64 + nt)*8 + dt; within chunk,
// lane = quad*16 + l16 holds V[d = dt*16+l16][s = nt*32 + quad*8 + j], j=0..7.
__global__ void vtrans_k(const bf16* __restrict__ in, bf16* __restrict__ out) {
  __shared__ bf16 tile[32][72];
  int tx = threadIdx.x, ty = threadIdx.y;  // (32,8)
  int s0 = blockIdx.x * 32, c0 = blockIdx.y * 64, bz = blockIdx.z;
  const bf16* src = in + (size_t)bz * 2048 * 2048;
#pragma unroll
  for (int j = 0; j < 4; ++j) {
    int sr = ty + j * 8;
    tile[sr][tx] = src[(size_t)(s0 + sr) * 2048 + c0 + tx];
    tile[sr][tx + 32] = src[(size_t)(s0 + sr) * 2048 + c0 + 32 + tx];
  }
  __syncthreads();
  int tid = ty * 32 + tx;
  int dl = tid & 63, srun = tid >> 6;
  int c = c0 + dl, hh = c >> 7, d = c & 127;
  int dt = d >> 4, lw = d & 15;
  union { bf16 e[8]; bf16x8 v; } pk;
#pragma unroll
  for (int k = 0; k < 8; ++k) pk.e[k] = tile[srun * 8 + k][dl];
  size_t bh = (size_t)bz * NH + hh;
  int nt = s0 >> 5;
  size_t idx = ((bh * 64 + nt) * 8 + dt) * 512 + (size_t)(srun * 16 + lw) * 8;
  *(bf16x8*)&out[idx] = pk.v;
}

// ---------------- GEMM: C(M,N) = A(M,K) @ Bt(N,K)^T ----------------
template <int BM, int BN, int KDIM, int MODE>
__global__ __launch_bounds__(256, 2) void gemm_bt(
    const bf16* __restrict__ A, const bf16* __restrict__ Bt, int Ndim,
    const float* __restrict__ bias_q, const float* __restrict__ bias_k,
    const float* __restrict__ bias_v, const float* __restrict__ bias_g,
    float* __restrict__ outCqk, bf16* __restrict__ out_v,
    float* __restrict__ out_g, float* __restrict__ outF) {
  __shared__ bf16 As[BM * 32];
  __shared__ bf16 Bs[BN * 32];
  const int tid = threadIdx.x;
  const int wave = tid >> 6, lane = tid & 63;
  const int quad = lane >> 4, l16 = lane & 15;
  const int m0 = blockIdx.y * BM, n0 = blockIdx.x * BN;
  constexpr int FI = BM / 32;
  constexpr int FJ = BN / 32;
  const int wm = (wave >> 1) * (BM / 2), wn = (wave & 1) * (BN / 2);

  floatx4 acc[FI][FJ] = {};

  for (int k0 = 0; k0 < KDIM; k0 += 32) {
#pragma unroll
    for (int j = 0; j < BM / 64; ++j) {
      int cbase = (j * 4 + wave) * 64;
      int c = cbase + lane;
      const bf16* g = A + (size_t)(m0 + (c >> 2)) * KDIM + k0 + (c & 3) * 8;
      ASYNC16(g, &As[cbase * 8]);
    }
#pragma unroll
    for (int j = 0; j < BN / 64; ++j) {
      int cbase = (j * 4 + wave) * 64;
      int c = cbase + lane;
      const bf16* g = Bt + (size_t)(n0 + (c >> 2)) * KDIM + k0 + (c & 3) * 8;
      ASYNC16(g, &Bs[cbase * 8]);
    }
    __syncthreads();  // compiler drains vmcnt(0) before s_barrier

    bf16x8 af[FI], bfr[FJ];
#pragma unroll
    for (int i = 0; i < FI; ++i)
      af[i] = *(const bf16x8*)&As[(wm + i * 16 + l16) * 32 + quad * 8];
#pragma unroll
    for (int j = 0; j < FJ; ++j)
      bfr[j] = *(const bf16x8*)&Bs[(wn + j * 16 + l16) * 32 + quad * 8];
#pragma unroll
    for (int i = 0; i < FI; ++i)
#pragma unroll
      for (int j = 0; j < FJ; ++j)
        acc[i][j] = MFMA16(af[i], bfr[j], acc[i][j]);
    __syncthreads();
  }

  // LEAN epilogue, all stores coalesced
#pragma unroll
  for (int i = 0; i < FI; ++i) {
#pragma unroll
    for (int j = 0; j < FJ; ++j) {
#pragma unroll
      for (int r = 0; r < 4; ++r) {
        int gm = m0 + wm + i * 16 + quad * 4 + r;
        int gn = n0 + wn + j * 16 + l16;
        float v = acc[i][j][r];
        if (MODE == 1) {
          v += bias_q[gn];  // bias_q = o_b
          outF[(size_t)gm * Ndim + gn] = v;
        } else {
          if (gn < 2048) {
            bool is_k = gn >= 1024;
            int jj = is_k ? gn - 1024 : gn;
            v += is_k ? bias_k[jj] : bias_q[jj];
            if (is_k) v *= 0.125f;  // SCALING = KEY_DIM^-0.5
            outCqk[(size_t)gm * 2048 + gn] = v;  // f32, exact
          } else if (gn < 4096) {
            int jj = gn - 2048;
            v += bias_v[jj];
            out_v[(size_t)gm * 2048 + jj] = f2b(v);  // natural layout
          } else {
            int jj = gn - 4096;
            v += bias_g[jj];
            out_g[(size_t)gm * 2048 + jj] = v;  // f32
          }
        }
      }
    }
  }
}

// ---------------- router: rotary + hi/lo split + layout (R12 version) -----
__global__ void router_k(const float* __restrict__ Cqk,
                         bf16* __restrict__ qh, bf16* __restrict__ ql,
                         bf16* __restrict__ kh, bf16* __restrict__ kl) {
  int t = blockIdx.x * 256 + threadIdx.x;  // 4096*1024 threads
  int row = t >> 10, pc = t & 1023;
  int b = row >> 11, s = row & 2047;
  bool is_k = pc >= 512;
  int jj = (pc - (is_k ? 512 : 0)) * 2;  // even, 0..1022
  int h = jj >> 6, d = jj & 63, ii = d >> 1;
  float2 v = *(const float2*)&Cqk[(size_t)row * 2048 + pc * 2];
  float half = exp2f(-(float)ii * (13.287712379549449f / 31.0f));
  float ang = (float)s * half;
  float sn = sinf(ang), cs = cosf(ang);
  float e = v.x * cs - v.y * sn;
  float o = v.y * cs + v.x * sn;
  bf16 eh = f2b(e), oh = f2b(o);
  bf16 el = f2b(e - b2f(eh)), ol = f2b(o - b2f(oh));
  size_t idx = (((size_t)b * NH + h) * SEQ + s) * KD + d;
  bf16* ph = is_k ? kh : qh;
  bf16* pl = is_k ? kl : ql;
  union { bf16 h2[2]; unsigned u; } uh, ul;
  uh.h2[0] = eh; uh.h2[1] = oh;
  ul.h2[0] = el; ul.h2[1] = ol;
  *(unsigned*)&ph[idx] = uh.u;
  *(unsigned*)&pl[idx] = ul.u;
}

// ---------------- retention core (R15: R12 + V direct-to-reg) ----------
// grid 1024 flat; bid -> (seg = bid>>5 -> h=seg&15, b=seg>>4), px_raw=bid&31.
// px = (seg bit3) ? 31-px_raw : px_raw. Block px owns TWO 32-row
// half-stripes: heavy bt_h=63-px, light bt_l=px. QK swapped (A=K, B=Q),
// P rebuilt in-register via permlane. K hi/lo staged in LDS (double-buffered,
// 4 chunks/wave); V loaded per-tile straight to registers from the
// fragment-ordered vf buffer (8 x global_load_dwordx4, coalesced).
__global__ __launch_bounds__(128, 2) void retention_k(
    const bf16* __restrict__ qh, const bf16* __restrict__ ql,
    const bf16* __restrict__ kh, const bf16* __restrict__ kl,
    const bf16* __restrict__ vf, const float* __restrict__ g,
    bf16* __restrict__ gated) {
  __shared__ bf16 KHs[2][32 * 64];
  __shared__ bf16 KLs[2][32 * 64];
  const int tid = threadIdx.x;
  const int wave = tid >> 6, lane = tid & 63;
  const int quad = lane >> 4, l16 = lane & 15;
  const int bid = blockIdx.x;
  const int px_raw = bid & 31;
  const int seg = bid >> 5;           // 0..31
  const int h = seg & 15, b = seg >> 4;
  const int px = ((seg >> 3) & 1) ? (31 - px_raw) : px_raw;
  const int bh = b * NH + h;
  const int bt_h = 63 - px;           // heavy half-stripe (32 rows)
  const int bt_l = px;                // light half-stripe
  const int m0h = bt_h * 32 + wave * 16;
  const int m0l = bt_l * 32 + wave * 16;
  const int ntiles = bt_h + 1;
  const int lt_ntiles = bt_l + 1;

  const float t = exp2f(-(float)(5 + h));  // 1-gamma (exact)
  const float lng = log1pf(-t);            // ln(gamma)
  const float log2g = lng * 1.44269504088896340736f;

  // per-lane row scalars (m = m0 + l16)
  float rfh, rfl;
  {
    int mh = m0h + l16, ml = m0l + l16;
    rfh = exp2f((float)mh * log2g) *
          rsqrtf(-expm1f((float)(mh + 1) * lng) / t);
    rfl = exp2f((float)ml * log2g) *
          rsqrtf(-expm1f((float)(ml + 1) * lng) / t);
  }
  const float gstep = exp2f(-32.0f * log2g);  // gamma^-32
  // per-lane col decay: n-offset = hh*16 + quad*4 + r
  float cfq[8];
#pragma unroll
  for (int i = 0; i < 8; ++i) {
    int hh = i >> 2, r = i & 3;
    cfq[i] = exp2f(-(float)(hh * 16 + quad * 4 + r) * log2g);
  }

  const size_t qoffh = ((size_t)bh * SEQ + m0h + l16) * KD;
  const size_t qoffl = ((size_t)bh * SEQ + m0l + l16) * KD;
  bf16x8 aq0h_h = *(const bf16x8*)&qh[qoffh + quad * 8];
  bf16x8 aq1h_h = *(const bf16x8*)&qh[qoffh + 32 + quad * 8];
  bf16x8 aq0l_h = *(const bf16x8*)&ql[qoffh + quad * 8];
  bf16x8 aq1l_h = *(const bf16x8*)&ql[qoffh + 32 + quad * 8];
  bf16x8 aq0h_l = *(const bf16x8*)&qh[qoffl + quad * 8];
  bf16x8 aq1h_l = *(const bf16x8*)&qh[qoffl + 32 + quad * 8];
  bf16x8 aq0l_l = *(const bf16x8*)&ql[qoffl + quad * 8];
  bf16x8 aq1l_l = *(const bf16x8*)&ql[qoffl + 32 + quad * 8];

  floatx4 oacch[8] = {}, oaccl[8] = {};
  float rsh = 0.f, rsl = 0.f;

  const bf16* khb = kh + (size_t)bh * SEQ * KD;
  const bf16* klb = kl + (size_t)bh * SEQ * KD;
  const bf16* vfb = vf + (size_t)bh * 64 * 8 * 512;
  const int lo8 = lane * 8;

  // K staging: 8 x 1KB chunks per tile over 2 waves (4 each):
  // wave0 -> KH (cc 0..3), wave1 -> KL (cc 4..7). Same swizzle as R12.
  auto stage = [&](int nt, int buf) {
    const int n0s = nt * 32;
#pragma unroll
    for (int j = 0; j < 4; ++j) {
      int cc = wave * 4 + j;
      const bf16* src = (cc < 4) ? khb : klb;
      bf16* dst = (cc < 4) ? KHs[buf] : KLs[buf];
      int r = ((cc & 3) * 8) + (lane >> 3);
      int s = lane & 7;
      int q = (s - r) & 7;
      ASYNC16(src + (size_t)(n0s + r) * KD + q * 8, &dst[(cc & 3) * 512]);
    }
  };

  // Build PV A-frag in-register from the transposed score tile (as R12).
  auto buildPA = [&](const floatx4* sc, float rf, float& rs, int n0,
                     int m0) -> bf16x8 {
    const int m = m0 + l16;
    const bool full = (m0 >= n0 + 31);  // tile fully below diagonal
    unsigned d[4];
#pragma unroll
    for (int hh = 0; hh < 2; ++hh) {
      float p[4];
#pragma unroll
      for (int r = 0; r < 4; ++r) {
        float pv;
        if (full) {
          pv = sc[hh][r] * rf * cfq[hh * 4 + r];
        } else {
          int n = n0 + hh * 16 + quad * 4 + r;
          pv = (m >= n) ? sc[hh][r] * rf * cfq[hh * 4 + r] : 0.f;
        }
        rs += pv;
        p[r] = pv;
      }
      union { bf16 hx[2]; unsigned u; } u0, u1;
      u0.hx[0] = f2b(p[0]); u0.hx[1] = f2b(p[1]);
      u1.hx[0] = f2b(p[2]); u1.hx[1] = f2b(p[3]);
      d[hh * 2 + 0] = u0.u;
      d[hh * 2 + 1] = u1.u;
    }
    unsigned a0 = d[0], b0 = d[2];  // (hh0 pair01, hh1 pair01)
    asm("v_permlane32_swap_b32 %0, %1" : "+v"(a0), "+v"(b0));
    asm("v_permlane16_swap_b32 %0, %1" : "+v"(a0), "+v"(b0));
    unsigned a1 = d[1], b1 = d[3];  // (hh0 pair23, hh1 pair23)
    asm("v_permlane32_swap_b32 %0, %1" : "+v"(a1), "+v"(b1));
    asm("v_permlane16_swap_b32 %0, %1" : "+v"(a1), "+v"(b1));
    union { unsigned u[4]; bf16x8 v; } pu;
    pu.u[0] = a0; pu.u[1] = a1; pu.u[2] = b0; pu.u[3] = b1;
    return pu.v;
  };

  stage(0, 0);
  for (int nt = 0; nt < ntiles; ++nt) {
    const int n0 = nt * 32;
    const int cur = nt & 1;
    asm volatile("s_waitcnt vmcnt(0) lgkmcnt(0)" ::: "memory");
    __syncthreads();

    // ---- V tile direct to registers (coalesced dwordx4; latency hides
    // under QK/buildPA; compiler's counted vmcnt keeps stage loads async) ----
    bf16x8 vv[8];
#pragma unroll
    for (int c = 0; c < 8; ++c)
      vv[c] = *(const bf16x8*)(vfb + ((size_t)nt * 8 + c) * 512 + lo8);

    {
      int pf = (nt + 1 < ntiles) ? nt + 1 : nt;
      stage(pf, cur ^ 1);
    }

    const bool hact = (n0 <= m0h + 15);
    const bool lact = (n0 <= m0l + 15);

    // ---- QK (SWAPPED: A=K-frag, B=Q-frag) for both stripes, sharing K ----
    floatx4 sch[2], scl[2];
#pragma unroll
    for (int hh = 0; hh < 2; ++hh) {
      int krow = hh * 16 + l16;
      int c0 = ((quad + krow) & 7) * 8;
      int c1 = ((quad + 4 + krow) & 7) * 8;
      bf16x8 bkh0 = *(const bf16x8*)&KHs[cur][krow * 64 + c0];
      bf16x8 bkh1 = *(const bf16x8*)&KHs[cur][krow * 64 + c1];
      bf16x8 bkl0 = *(const bf16x8*)&KLs[cur][krow * 64 + c0];
      bf16x8 bkl1 = *(const bf16x8*)&KLs[cur][krow * 64 + c1];
      if (hact) {
        floatx4 z1 = {0.f, 0.f, 0.f, 0.f}, z2 = z1, z3 = z1;
        z1 = MFMA16(bkh0, aq0h_h, z1);
        z2 = MFMA16(bkh0, aq0l_h, z2);
        z3 = MFMA16(bkl0, aq0h_h, z3);
        z1 = MFMA16(bkh1, aq1h_h, z1);
        z2 = MFMA16(bkh1, aq1l_h, z2);
        z3 = MFMA16(bkl1, aq1h_h, z3);
        sch[hh] = z1 + z2 + z3;
      }
      if (lact) {
        floatx4 z1 = {0.f, 0.f, 0.f, 0.f}, z2 = z1, z3 = z1;
        z1 = MFMA16(bkh0, aq0h_l, z1);
        z2 = MFMA16(bkh0, aq0l_l, z2);
        z3 = MFMA16(bkl0, aq0h_l, z3);
        z1 = MFMA16(bkh1, aq1h_l, z1);
        z2 = MFMA16(bkh1, aq1l_l, z2);
        z3 = MFMA16(bkl1, aq1h_l, z3);
        scl[hh] = z1 + z2 + z3;
      }
    }

    // ---- decay mask + row sums + PA rebuild, all in-register ----
    bf16x8 pah, pal;
    if (hact) pah = buildPA(sch, rfh, rsh, n0, m0h);
    if (lact) pal = buildPA(scl, rfl, rsl, n0, m0l);
    rfh *= gstep;
    if (nt + 1 < lt_ntiles) rfl *= gstep;

    // ---- PV for both stripes, sharing V registers ----
#pragma unroll
    for (int dt = 0; dt < 8; ++dt) {
      if (hact) oacch[dt] = MFMA16(pah, vv[dt], oacch[dt]);
      if (lact) oaccl[dt] = MFMA16(pal, vv[dt], oaccl[dt]);
    }
  }

  // ---- epilogue: denom clip, groupnorm(128), silu gate — per stripe ----
  auto finalize = [&](floatx4* oacc, float rowsum, int m0) {
    float v = rowsum;
    v += __shfl_xor(v, 16);
    v += __shfl_xor(v, 32);
    float inv_den[4];
#pragma unroll
    for (int r = 0; r < 4; ++r) {
      float dsum = __shfl(v, quad * 4 + r);
      inv_den[r] = 1.0f / fmaxf(fabsf(dsum), 1.0f);
    }
    float s1[4] = {}, s2[4] = {};
#pragma unroll
    for (int dt = 0; dt < 8; ++dt) {
#pragma unroll
      for (int r = 0; r < 4; ++r) {
        float vv2 = oacc[dt][r] * inv_den[r];
        oacc[dt][r] = vv2;
        s1[r] += vv2;
        s2[r] += vv2 * vv2;
      }
    }
    float mean[4], istd[4];
#pragma unroll
    for (int r = 0; r < 4; ++r) {
      float a = s1[r], q2 = s2[r];
      a += __shfl_xor(a, 1); a += __shfl_xor(a, 2);
      a += __shfl_xor(a, 4); a += __shfl_xor(a, 8);
      q2 += __shfl_xor(q2, 1); q2 += __shfl_xor(q2, 2);
      q2 += __shfl_xor(q2, 4); q2 += __shfl_xor(q2, 8);
      mean[r] = a * (1.0f / 128.0f);
      float var = q2 * (1.0f / 128.0f) - mean[r] * mean[r];
      istd[r] = rsqrtf(fmaxf(var, 0.0f) + 1e-5f);
    }
#pragma unroll
    for (int dt = 0; dt < 8; ++dt) {
#pragma unroll
      for (int r = 0; r < 4; ++r) {
        int m = m0 + quad * 4 + r;
        int col = h * HD + dt * 16 + l16;
        float vv2 = (oacc[dt][r] - mean[r]) * istd[r];
        float gv = g[((size_t)b * SEQ + m) * 2048 + col];
        float sg = gv / (1.0f + expf(-gv));
        gated[((size_t)b * SEQ + m) * 2048 + col] = f2b(sg * vv2);
      }
    }
  };
  finalize(oacch, rsh, m0h);
  finalize(oaccl, rsl, m0l);
}

// ---------------- launch ----------------
extern "C" void kernel_launch(void* const* d_in, const int* in_sizes, int n_in,
                              void* d_out, int out_size, void* d_ws,
                              size_t ws_size, hipStream_t stream) {
  const float* x   = (const float*)d_in[0];
  const float* q_w = (const float*)d_in[1];
  const float* q_b = (const float*)d_in[2];
  const float* k_w = (const float*)d_in[3];
  const float* k_b = (const float*)d_in[4];
  const float* v_w = (const float*)d_in[5];
  const float* v_b = (const float*)d_in[6];
  const float* g_w = (const float*)d_in[7];
  const float* g_b = (const float*)d_in[8];
  const float* o_w = (const float*)d_in[9];
  const float* o_b = (const float*)d_in[10];

  char* ws = (char*)d_ws;
  bf16* Wt    = (bf16*)ws; ws += (size_t)6144 * 1024 * 2;
  bf16* oT    = (bf16*)ws; ws += (size_t)1024 * 2048 * 2;
  bf16* xb    = (bf16*)ws; ws += (size_t)4096 * 1024 * 2;
  float* Cqk  = (float*)ws; ws += (size_t)4096 * 2048 * 4;
  bf16* qhb   = (bf16*)ws; ws += (size_t)32 * 2048 * 64 * 2;
  bf16* qlb   = (bf16*)ws; ws += (size_t)32 * 2048 * 64 * 2;
  bf16* khb   = (bf16*)ws; ws += (size_t)32 * 2048 * 64 * 2;
  bf16* klb   = (bf16*)ws; ws += (size_t)32 * 2048 * 64 * 2;
  bf16* vfb   = (bf16*)ws; ws += (size_t)32 * 64 * 8 * 512 * 2;  // 16.78 MB (vTb's slot)
  float* gbuf = (float*)ws; ws += (size_t)2 * 2048 * 2048 * 4;
  bf16* gated = (bf16*)ws; ws += (size_t)4096 * 2048 * 2;
  // vbuf aliases gated: vbuf lives GEMM1->vtrans, gated lives retention->GEMM2
  bf16* vbuf  = gated;

  convert_k<<<(4096 * 1024 / 4) / 256, 256, 0, stream>>>(x, xb);

  dim3 tb(32, 8);
  transpose_k<<<dim3(1024 / 32, 1024 / 32), tb, 0, stream>>>(q_w, Wt, 1024, 1024);
  transpose_k<<<dim3(1024 / 32, 1024 / 32), tb, 0, stream>>>(k_w, Wt + (size_t)1024 * 1024, 1024, 1024);
  transpose_k<<<dim3(2048 / 32, 1024 / 32), tb, 0, stream>>>(v_w, Wt + (size_t)2048 * 1024, 1024, 2048);
  transpose_k<<<dim3(2048 / 32, 1024 / 32), tb, 0, stream>>>(g_w, Wt + (size_t)4096 * 1024, 1024, 2048);
  transpose_k<<<dim3(1024 / 32, 2048 / 32), tb, 0, stream>>>(o_w, oT, 2048, 1024);

  gemm_bt<128, 128, 1024, 0><<<dim3(6144 / 128, 4096 / 128), 256, 0, stream>>>(
      xb, Wt, 6144, q_b, k_b, v_b, g_b, Cqk, vbuf, gbuf, nullptr);

  vtrans_k<<<dim3(2048 / 32, 2048 / 64, B_SZ), tb, 0, stream>>>(vbuf, vfb);

  router_k<<<(4096 * 1024) / 256, 256, 0, stream>>>(Cqk, qhb, qlb, khb, klb);

  retention_k<<<dim3(1024), 128, 0, stream>>>(
      qhb, qlb, khb, klb, vfb, gbuf, gated);

  gemm_bt<128, 64, 2048, 1><<<dim3(1024 / 64, 4096 / 128), 256, 0, stream>>>(
      gated, oT, 1024, o_b, nullptr, nullptr, nullptr, nullptr, nullptr,
      nullptr, (float*)d_out);
}